// Round 1
// baseline (89.570 us; speedup 1.0000x reference)
//
#include <hip/hip_runtime.h>

// scores[b,s] = sum_d enc[b,s,d] * dec[b,d]
// B=64, S=2048, D=1024 (fp32). Memory-bound: enc is 512 MiB read-once.

constexpr int B = 64;
constexpr int S = 2048;
constexpr int D = 1024;
constexpr int WAVES_PER_BLOCK = 4;   // 256 threads

__global__ __launch_bounds__(256) void attn_scores_kernel(
    const float* __restrict__ dec,   // [B, D]
    const float* __restrict__ enc,   // [B, S, D]
    float* __restrict__ out)         // [B, S]
{
    const int wave = threadIdx.x >> 6;
    const int lane = threadIdx.x & 63;
    const long row = (long)blockIdx.x * WAVES_PER_BLOCK + wave;  // row in [0, B*S)
    if (row >= (long)B * S) return;

    const int b = (int)(row >> 11);  // row / S, S = 2048

    const float4* __restrict__ erow = (const float4*)(enc + row * (long)D);
    const float4* __restrict__ dvec = (const float4*)(dec + (long)b * D);

    float acc = 0.0f;
#pragma unroll
    for (int it = 0; it < D / (64 * 4); ++it) {   // 4 iterations
        const float4 e = erow[lane + it * 64];
        const float4 d = dvec[lane + it * 64];
        acc += e.x * d.x + e.y * d.y + e.z * d.z + e.w * d.w;
    }

    // 64-lane wave reduction
#pragma unroll
    for (int off = 32; off >= 1; off >>= 1)
        acc += __shfl_down(acc, off, 64);

    if (lane == 0)
        out[row] = acc;
}

extern "C" void kernel_launch(void* const* d_in, const int* in_sizes, int n_in,
                              void* d_out, int out_size, void* d_ws, size_t ws_size,
                              hipStream_t stream) {
    const float* dec = (const float*)d_in[0];   // [64, 1024]
    const float* enc = (const float*)d_in[1];   // [64, 2048, 1024]
    float* out = (float*)d_out;                 // [64, 1, 2048]

    const int total_rows = B * S;               // 131072
    const int blocks = total_rows / WAVES_PER_BLOCK;  // 32768
    attn_scores_kernel<<<blocks, 256, 0, stream>>>(dec, enc, out);
}

// Round 3
// 81.016 us; speedup vs baseline: 1.1056x; 1.1056x over previous
//
#include <hip/hip_runtime.h>

// scores[b,s] = sum_d enc[b,s,d] * dec[b,d]
// B=64, S=2048, D=1024 (fp32). Memory-bound: enc is 512 MiB read-once.
// v2b: 2 rows per wave (dec register-reuse, 2x MLP) + nontemporal enc loads.
//      Uses native clang ext_vector float4 (HIP float4 class rejected by
//      __builtin_nontemporal_load).

typedef float f32x4 __attribute__((ext_vector_type(4)));

constexpr int B = 64;
constexpr int S = 2048;
constexpr int D = 1024;
constexpr int WAVES_PER_BLOCK = 4;     // 256 threads
constexpr int ROWS_PER_WAVE = 2;       // 8 rows per block

__global__ __launch_bounds__(256) void attn_scores_kernel(
    const float* __restrict__ dec,   // [B, D]
    const float* __restrict__ enc,   // [B, S, D]
    float* __restrict__ out)         // [B, S]
{
    const int wave = threadIdx.x >> 6;
    const int lane = threadIdx.x & 63;

    // Each wave owns 2 consecutive rows. S is even, so the pair never
    // straddles a batch boundary.
    const long row0 = ((long)blockIdx.x * WAVES_PER_BLOCK + wave) * ROWS_PER_WAVE;
    const int b = (int)(row0 >> 11);   // row / S, S = 2048

    const f32x4* __restrict__ e0 = (const f32x4*)(enc + row0 * (long)D);
    const f32x4* __restrict__ e1 = e0 + (D / 4);
    const f32x4* __restrict__ dvec = (const f32x4*)(dec + (long)b * D);

    // dec fragment: loaded once, reused for both rows (L1/L2-resident).
    f32x4 dv[4];
#pragma unroll
    for (int it = 0; it < 4; ++it)
        dv[it] = dvec[lane + it * 64];

    float acc0 = 0.0f, acc1 = 0.0f;
#pragma unroll
    for (int it = 0; it < 4; ++it) {
        const f32x4 a = __builtin_nontemporal_load(&e0[lane + it * 64]);
        const f32x4 c = __builtin_nontemporal_load(&e1[lane + it * 64]);
        acc0 += a.x * dv[it].x + a.y * dv[it].y + a.z * dv[it].z + a.w * dv[it].w;
        acc1 += c.x * dv[it].x + c.y * dv[it].y + c.z * dv[it].z + c.w * dv[it].w;
    }

    // 64-lane wave reductions
#pragma unroll
    for (int off = 32; off >= 1; off >>= 1) {
        acc0 += __shfl_down(acc0, off, 64);
        acc1 += __shfl_down(acc1, off, 64);
    }

    if (lane == 0) {
        out[row0] = acc0;
        out[row0 + 1] = acc1;
    }
}

extern "C" void kernel_launch(void* const* d_in, const int* in_sizes, int n_in,
                              void* d_out, int out_size, void* d_ws, size_t ws_size,
                              hipStream_t stream) {
    const float* dec = (const float*)d_in[0];   // [64, 1024]
    const float* enc = (const float*)d_in[1];   // [64, 2048, 1024]
    float* out = (float*)d_out;                 // [64, 1, 2048]

    const int total_rows = B * S;                                   // 131072
    const int blocks = total_rows / (WAVES_PER_BLOCK * ROWS_PER_WAVE);  // 16384
    attn_scores_kernel<<<blocks, 256, 0, stream>>>(dec, enc, out);
}